// Round 1
// baseline (11249.851 us; speedup 1.0000x reference)
//
#include <hip/hip_runtime.h>
#include <cstddef>

#define SLOPE_F (11.0f / 48.0f)

static const int NN = 50000;     // nodes
static const int EE = 1600000;   // edges per timestep
static const int D  = 256;

// ---------------- prep: merged GRU weights + Q init ----------------
__global__ void prep_kernel(const float* __restrict__ Wz0, const float* __restrict__ Uz0,
                            const float* __restrict__ Wr0, const float* __restrict__ Ur0,
                            const float* __restrict__ Q00,
                            const float* __restrict__ Wz1, const float* __restrict__ Uz1,
                            const float* __restrict__ Wr1, const float* __restrict__ Ur1,
                            const float* __restrict__ Q01,
                            float* __restrict__ Mz0, float* __restrict__ Mr0, float* __restrict__ q0,
                            float* __restrict__ Mz1, float* __restrict__ Mr1, float* __restrict__ q1) {
    int i = blockIdx.x * blockDim.x + threadIdx.x;   // 65536 total
    Mz0[i] = Wz0[i] + Uz0[i];
    Mr0[i] = Wr0[i] + Ur0[i];
    q0[i]  = Q00[i];
    Mz1[i] = Wz1[i] + Uz1[i];
    Mr1[i] = Wr1[i] + Ur1[i];
    q1[i]  = Q01[i];
}

// ---------------- GRU step part A: z, r*Q, Wh@Q ----------------
// block = row i (256 blocks), thread = col j (256 threads)
__global__ void gruA_kernel(const float* __restrict__ Mz, const float* __restrict__ Mr,
                            const float* __restrict__ Wh,
                            const float* __restrict__ bz, const float* __restrict__ br,
                            const float* __restrict__ Q,
                            float* __restrict__ zb, float* __restrict__ RQ,
                            float* __restrict__ WhQ) {
    int i = blockIdx.x;
    int j = threadIdx.x;
    float az = 0.f, ar = 0.f, ah = 0.f;
    for (int k = 0; k < D; ++k) {
        float q  = Q[k * D + j];       // coalesced across j
        float mz = Mz[i * D + k];      // uniform per block -> scalar load
        float mr = Mr[i * D + k];
        float wh = Wh[i * D + k];
        az += mz * q;
        ar += mr * q;
        ah += wh * q;
    }
    float zz = 1.f / (1.f + expf(-(az + bz[i * D + j])));
    float rr = 1.f / (1.f + expf(-(ar + br[i * D + j])));
    zb[i * D + j]  = zz;
    RQ[i * D + j]  = rr * Q[i * D + j];
    WhQ[i * D + j] = ah;
}

// ---------------- GRU step part B: h, Q update (in-place) ----------------
__global__ void gruB_kernel(const float* __restrict__ Uh, const float* __restrict__ bh,
                            const float* __restrict__ zb, const float* __restrict__ RQ,
                            const float* __restrict__ WhQ,
                            float* __restrict__ Q) {
    int i = blockIdx.x;
    int j = threadIdx.x;
    float acc = 0.f;
    for (int k = 0; k < D; ++k)
        acc += Uh[i * D + k] * RQ[k * D + j];
    float h  = tanhf(WhQ[i * D + j] + acc + bh[i * D + j]);
    float zz = zb[i * D + j];
    float q  = Q[i * D + j];
    Q[i * D + j] = (1.f - zz) * q + zz * h;   // safe: this thread is sole reader/writer
}

// ---------------- GEMM: C[M,256] = A[M,256] @ B[256,256] (+optional bias/relu) ----------------
// 64x64 tile, BK=32, 256 threads, 4x4 accum per thread. A staged transposed in LDS.
template <int EPI>   // 0 = plain, 1 = bias + relu
__global__ __launch_bounds__(256) void gemm_k(const float* __restrict__ A,
                                              const float* __restrict__ B,
                                              const float* __restrict__ bias,
                                              float* __restrict__ C, int M) {
    __shared__ float As[32][64];   // [k][m] (transposed)
    __shared__ float Bs[32][64];   // [k][n]
    int tid = threadIdx.x;
    int tx = tid & 15, ty = tid >> 4;
    int bm = blockIdx.x, bn = blockIdx.y;
    int row0 = bm * 64;

    float acc[4][4] = {};

    for (int kc = 0; kc < 8; ++kc) {
        __syncthreads();
#pragma unroll
        for (int l = 0; l < 2; ++l) {
            int q  = tid + l * 256;
            int r  = q >> 3;            // 0..63 (m within tile)
            int kq = (q & 7) << 2;      // 0,4,...,28 (k within chunk)
            int gr = row0 + r;
            float4 v = make_float4(0.f, 0.f, 0.f, 0.f);
            if (gr < M) v = *(const float4*)&A[(size_t)gr * D + kc * 32 + kq];
            As[kq + 0][r] = v.x;
            As[kq + 1][r] = v.y;
            As[kq + 2][r] = v.z;
            As[kq + 3][r] = v.w;
        }
#pragma unroll
        for (int l = 0; l < 2; ++l) {
            int q  = tid + l * 256;
            int kr = q >> 4;            // 0..31
            int nq = (q & 15) << 2;     // 0..60
            *(float4*)&Bs[kr][nq] = *(const float4*)&B[(size_t)(kc * 32 + kr) * D + bn * 64 + nq];
        }
        __syncthreads();
#pragma unroll
        for (int kk = 0; kk < 32; ++kk) {
            float4 a = *(const float4*)&As[kk][ty * 4];
            float4 b = *(const float4*)&Bs[kk][tx * 4];
            float av[4] = {a.x, a.y, a.z, a.w};
            float bv[4] = {b.x, b.y, b.z, b.w};
#pragma unroll
            for (int i = 0; i < 4; ++i)
#pragma unroll
                for (int j = 0; j < 4; ++j)
                    acc[i][j] += av[i] * bv[j];
        }
    }

    int col0 = bn * 64 + tx * 4;
#pragma unroll
    for (int i = 0; i < 4; ++i) {
        int gr = row0 + ty * 4 + i;
        if (gr < M) {
            float4 o;
            if (EPI == 1) {
                o.x = fmaxf(acc[i][0] + bias[col0 + 0], 0.f);
                o.y = fmaxf(acc[i][1] + bias[col0 + 1], 0.f);
                o.z = fmaxf(acc[i][2] + bias[col0 + 2], 0.f);
                o.w = fmaxf(acc[i][3] + bias[col0 + 3], 0.f);
            } else {
                o = make_float4(acc[i][0], acc[i][1], acc[i][2], acc[i][3]);
            }
            *(float4*)&C[(size_t)gr * D + col0] = o;
        }
    }
}

// ---------------- zero ----------------
__global__ void zero_kernel(float4* __restrict__ p, int n4) {
    int i = blockIdx.x * blockDim.x + threadIdx.x;
    if (i < n4) p[i] = make_float4(0.f, 0.f, 0.f, 0.f);
}

// ---------------- edge aggregation: agg[dst] += val * XW[src] ----------------
// one wave (64 lanes) per edge; lane covers 4 consecutive features (float4)
__global__ void agg_kernel(const float* __restrict__ XW, const int* __restrict__ src,
                           const int* __restrict__ dst, const float* __restrict__ val,
                           float* __restrict__ agg, int nE) {
    int e = blockIdx.x * 4 + (threadIdx.x >> 6);
    if (e >= nE) return;
    int lane = threadIdx.x & 63;
    int s = src[e];
    int d = dst[e];
    float v = val[e];
    float4 x = *(const float4*)&XW[(size_t)s * D + lane * 4];
    float* o = &agg[(size_t)d * D + lane * 4];
    atomicAdd(o + 0, v * x.x);
    atomicAdd(o + 1, v * x.y);
    atomicAdd(o + 2, v * x.z);
    atomicAdd(o + 3, v * x.w);
}

// ---------------- RReLU (eval) in-place ----------------
__global__ void rrelu_kernel(float4* __restrict__ p, int n4) {
    int i = blockIdx.x * blockDim.x + threadIdx.x;
    if (i < n4) {
        float4 v = p[i];
        v.x = (v.x >= 0.f) ? v.x : SLOPE_F * v.x;
        v.y = (v.y >= 0.f) ? v.y : SLOPE_F * v.y;
        v.z = (v.z >= 0.f) ? v.z : SLOPE_F * v.z;
        v.w = (v.w >= 0.f) ? v.w : SLOPE_F * v.w;
        p[i] = v;
    }
}

// ---------------- final: logits = hid@W2 + b2 ; log_softmax over 16 classes ----------------
// 16 nodes per block; 16 lanes per node (one class each)
__global__ void mlp2_kernel(const float* __restrict__ hid, const float* __restrict__ W2,
                            const float* __restrict__ b2, float* __restrict__ out, int M) {
    int tid = threadIdx.x;
    int n = blockIdx.x * 16 + (tid >> 4);
    int c = tid & 15;
    if (n >= M) return;
    float acc = b2[c];
    for (int k = 0; k < D; ++k)
        acc += hid[(size_t)n * D + k] * W2[k * 16 + c];
    float m = acc;
#pragma unroll
    for (int off = 1; off < 16; off <<= 1)
        m = fmaxf(m, __shfl_xor(m, off, 16));
    float ex = expf(acc - m);
    float s = ex;
#pragma unroll
    for (int off = 1; off < 16; off <<= 1)
        s += __shfl_xor(s, off, 16);
    out[(size_t)n * 16 + c] = acc - m - logf(s);
}

extern "C" void kernel_launch(void* const* d_in, const int* in_sizes, int n_in,
                              void* d_out, int out_size, void* d_ws, size_t ws_size,
                              hipStream_t stream) {
    const float* node_feats = (const float*)d_in[0];
    const float* edge_val   = (const float*)d_in[1];
    const float* l0_Wz = (const float*)d_in[2];
    const float* l0_Uz = (const float*)d_in[3];
    const float* l0_bz = (const float*)d_in[4];
    const float* l0_Wr = (const float*)d_in[5];
    const float* l0_Ur = (const float*)d_in[6];
    const float* l0_br = (const float*)d_in[7];
    const float* l0_Wh = (const float*)d_in[8];
    const float* l0_Uh = (const float*)d_in[9];
    const float* l0_bh = (const float*)d_in[10];
    const float* l0_Q0 = (const float*)d_in[11];
    const float* l1_Wz = (const float*)d_in[12];
    const float* l1_Uz = (const float*)d_in[13];
    const float* l1_bz = (const float*)d_in[14];
    const float* l1_Wr = (const float*)d_in[15];
    const float* l1_Ur = (const float*)d_in[16];
    const float* l1_br = (const float*)d_in[17];
    const float* l1_Wh = (const float*)d_in[18];
    const float* l1_Uh = (const float*)d_in[19];
    const float* l1_bh = (const float*)d_in[20];
    const float* l1_Q0 = (const float*)d_in[21];
    const float* W1 = (const float*)d_in[22];
    const float* b1 = (const float*)d_in[23];
    const float* W2 = (const float*)d_in[24];
    const float* b2 = (const float*)d_in[25];
    const int* e_src = (const int*)d_in[26];
    const int* e_dst = (const int*)d_in[27];
    float* out = (float*)d_out;

    // workspace layout (floats): two big ping-pong buffers + GRU scratch
    const size_t BIG = (size_t)NN * D;   // 12.8M floats
    float* ws   = (float*)d_ws;
    float* X    = ws;                    // GEMM outputs (XW / hid)
    float* Y    = ws + BIG;              // aggregation outputs (h1 / h2)
    float* sm   = ws + 2 * BIG;
    float* Mz0  = sm + 0 * 65536;
    float* Mr0  = sm + 1 * 65536;
    float* q0   = sm + 2 * 65536;
    float* Mz1  = sm + 3 * 65536;
    float* Mr1  = sm + 4 * 65536;
    float* q1   = sm + 5 * 65536;
    float* zb   = sm + 6 * 65536;
    float* RQ   = sm + 7 * 65536;
    float* WhQ  = sm + 8 * 65536;

    // --- weight evolution (only the final Q matters for the output) ---
    prep_kernel<<<256, 256, 0, stream>>>(l0_Wz, l0_Uz, l0_Wr, l0_Ur, l0_Q0,
                                         l1_Wz, l1_Uz, l1_Wr, l1_Ur, l1_Q0,
                                         Mz0, Mr0, q0, Mz1, Mr1, q1);
    for (int t = 0; t < 6; ++t) {
        gruA_kernel<<<256, 256, 0, stream>>>(Mz0, Mr0, l0_Wh, l0_bz, l0_br, q0, zb, RQ, WhQ);
        gruB_kernel<<<256, 256, 0, stream>>>(l0_Uh, l0_bh, zb, RQ, WhQ, q0);
    }
    for (int t = 0; t < 6; ++t) {
        gruA_kernel<<<256, 256, 0, stream>>>(Mz1, Mr1, l1_Wh, l1_bz, l1_br, q1, zb, RQ, WhQ);
        gruB_kernel<<<256, 256, 0, stream>>>(l1_Uh, l1_bh, zb, RQ, WhQ, q1);
    }

    // --- only timestep 5 contributes to the output ---
    const float* feats5 = node_feats + (size_t)5 * BIG;
    const int*   src5   = e_src + (size_t)5 * EE;
    const int*   dst5   = e_dst + (size_t)5 * EE;
    const float* val5   = edge_val + (size_t)5 * EE;

    dim3 gemm_grid((NN + 63) / 64, 4);
    const int N4 = (int)(BIG / 4);           // 3.2M float4
    const int zblocks = (N4 + 255) / 256;    // 12500
    const int eblocks = EE / 4;              // 400000

    // layer 0 @ t=5
    gemm_k<0><<<gemm_grid, 256, 0, stream>>>(feats5, q0, nullptr, X, NN);
    zero_kernel<<<zblocks, 256, 0, stream>>>((float4*)Y, N4);
    agg_kernel<<<eblocks, 256, 0, stream>>>(X, src5, dst5, val5, Y, EE);
    rrelu_kernel<<<zblocks, 256, 0, stream>>>((float4*)Y, N4);

    // layer 1 @ t=5
    gemm_k<0><<<gemm_grid, 256, 0, stream>>>(Y, q1, nullptr, X, NN);
    zero_kernel<<<zblocks, 256, 0, stream>>>((float4*)Y, N4);
    agg_kernel<<<eblocks, 256, 0, stream>>>(X, src5, dst5, val5, Y, EE);
    rrelu_kernel<<<zblocks, 256, 0, stream>>>((float4*)Y, N4);

    // MLP head
    gemm_k<1><<<gemm_grid, 256, 0, stream>>>(Y, W1, b1, X, NN);
    mlp2_kernel<<<(NN + 15) / 16, 256, 0, stream>>>(X, W2, b2, out, NN);
}

// Round 2
// 1162.094 us; speedup vs baseline: 9.6807x; 9.6807x over previous
//
#include <hip/hip_runtime.h>
#include <cstddef>

#define SLOPE_F (11.0f / 48.0f)

static const int NN = 50000;     // nodes
static const int EE = 1600000;   // edges per timestep
static const int D  = 256;

// ---------------- prep: merged GRU weights + Q init ----------------
__global__ void prep_kernel(const float* __restrict__ Wz0, const float* __restrict__ Uz0,
                            const float* __restrict__ Wr0, const float* __restrict__ Ur0,
                            const float* __restrict__ Q00,
                            const float* __restrict__ Wz1, const float* __restrict__ Uz1,
                            const float* __restrict__ Wr1, const float* __restrict__ Ur1,
                            const float* __restrict__ Q01,
                            float* __restrict__ Mz0, float* __restrict__ Mr0, float* __restrict__ q0,
                            float* __restrict__ Mz1, float* __restrict__ Mr1, float* __restrict__ q1) {
    int i = blockIdx.x * blockDim.x + threadIdx.x;   // 65536 total
    Mz0[i] = Wz0[i] + Uz0[i];
    Mr0[i] = Wr0[i] + Ur0[i];
    q0[i]  = Q00[i];
    Mz1[i] = Wz1[i] + Uz1[i];
    Mr1[i] = Wr1[i] + Ur1[i];
    q1[i]  = Q01[i];
}

// ---------------- GRU step part A (both layers): z, r*Q, Wh@Q ----------------
// blockIdx [0,512): layer = blk>>8, row i = blk&255; thread = col j
__global__ void gruA_kernel(const float* __restrict__ Mz0, const float* __restrict__ Mr0,
                            const float* __restrict__ Wh0, const float* __restrict__ bz0,
                            const float* __restrict__ br0, const float* __restrict__ Q0,
                            const float* __restrict__ Mz1, const float* __restrict__ Mr1,
                            const float* __restrict__ Wh1, const float* __restrict__ bz1,
                            const float* __restrict__ br1, const float* __restrict__ Q1,
                            float* __restrict__ zb, float* __restrict__ RQ,
                            float* __restrict__ WhQ) {
    int layer = blockIdx.x >> 8;
    int i = blockIdx.x & 255;
    int j = threadIdx.x;
    const float* Mz = layer ? Mz1 : Mz0;
    const float* Mr = layer ? Mr1 : Mr0;
    const float* Wh = layer ? Wh1 : Wh0;
    const float* bz = layer ? bz1 : bz0;
    const float* br = layer ? br1 : br0;
    const float* Q  = layer ? Q1  : Q0;
    float az = 0.f, ar = 0.f, ah = 0.f;
    for (int k = 0; k < D; ++k) {
        float q  = Q[k * D + j];       // coalesced across j
        az += Mz[i * D + k] * q;
        ar += Mr[i * D + k] * q;
        ah += Wh[i * D + k] * q;
    }
    float zz = 1.f / (1.f + expf(-(az + bz[i * D + j])));
    float rr = 1.f / (1.f + expf(-(ar + br[i * D + j])));
    size_t o = (size_t)layer * 65536 + i * D + j;
    zb[o]  = zz;
    RQ[o]  = rr * Q[i * D + j];
    WhQ[o] = ah;
}

// ---------------- GRU step part B (both layers): h, Q update (in-place) ----------------
__global__ void gruB_kernel(const float* __restrict__ Uh0, const float* __restrict__ bh0,
                            float* __restrict__ Q0,
                            const float* __restrict__ Uh1, const float* __restrict__ bh1,
                            float* __restrict__ Q1,
                            const float* __restrict__ zb, const float* __restrict__ RQ,
                            const float* __restrict__ WhQ) {
    int layer = blockIdx.x >> 8;
    int i = blockIdx.x & 255;
    int j = threadIdx.x;
    const float* Uh = layer ? Uh1 : Uh0;
    const float* bh = layer ? bh1 : bh0;
    float* Q = layer ? Q1 : Q0;
    const float* RQl = RQ + (size_t)layer * 65536;
    float acc = 0.f;
    for (int k = 0; k < D; ++k)
        acc += Uh[i * D + k] * RQl[k * D + j];
    size_t o = (size_t)layer * 65536 + i * D + j;
    float h  = tanhf(WhQ[o] + acc + bh[i * D + j]);
    float zz = zb[o];
    float q  = Q[i * D + j];
    Q[i * D + j] = (1.f - zz) * q + zz * h;
}

// ---------------- GEMM: C[M,256] = A[M,256] @ B[256,256] (+optional bias/relu) ----------------
template <int EPI>   // 0 = plain, 1 = bias + relu
__global__ __launch_bounds__(256) void gemm_k(const float* __restrict__ A,
                                              const float* __restrict__ B,
                                              const float* __restrict__ bias,
                                              float* __restrict__ C, int M) {
    __shared__ float As[32][64];   // [k][m] (transposed)
    __shared__ float Bs[32][64];   // [k][n]
    int tid = threadIdx.x;
    int tx = tid & 15, ty = tid >> 4;
    int bm = blockIdx.x, bn = blockIdx.y;
    int row0 = bm * 64;

    float acc[4][4] = {};

    for (int kc = 0; kc < 8; ++kc) {
        __syncthreads();
#pragma unroll
        for (int l = 0; l < 2; ++l) {
            int q  = tid + l * 256;
            int r  = q >> 3;            // 0..63 (m within tile)
            int kq = (q & 7) << 2;      // 0,4,...,28
            int gr = row0 + r;
            float4 v = make_float4(0.f, 0.f, 0.f, 0.f);
            if (gr < M) v = *(const float4*)&A[(size_t)gr * D + kc * 32 + kq];
            As[kq + 0][r] = v.x;
            As[kq + 1][r] = v.y;
            As[kq + 2][r] = v.z;
            As[kq + 3][r] = v.w;
        }
#pragma unroll
        for (int l = 0; l < 2; ++l) {
            int q  = tid + l * 256;
            int kr = q >> 4;            // 0..31
            int nq = (q & 15) << 2;     // 0..60
            *(float4*)&Bs[kr][nq] = *(const float4*)&B[(size_t)(kc * 32 + kr) * D + bn * 64 + nq];
        }
        __syncthreads();
#pragma unroll
        for (int kk = 0; kk < 32; ++kk) {
            float4 a = *(const float4*)&As[kk][ty * 4];
            float4 b = *(const float4*)&Bs[kk][tx * 4];
            float av[4] = {a.x, a.y, a.z, a.w};
            float bv[4] = {b.x, b.y, b.z, b.w};
#pragma unroll
            for (int i = 0; i < 4; ++i)
#pragma unroll
                for (int j = 0; j < 4; ++j)
                    acc[i][j] += av[i] * bv[j];
        }
    }

    int col0 = bn * 64 + tx * 4;
#pragma unroll
    for (int i = 0; i < 4; ++i) {
        int gr = row0 + ty * 4 + i;
        if (gr < M) {
            float4 o;
            if (EPI == 1) {
                o.x = fmaxf(acc[i][0] + bias[col0 + 0], 0.f);
                o.y = fmaxf(acc[i][1] + bias[col0 + 1], 0.f);
                o.z = fmaxf(acc[i][2] + bias[col0 + 2], 0.f);
                o.w = fmaxf(acc[i][3] + bias[col0 + 3], 0.f);
            } else {
                o = make_float4(acc[i][0], acc[i][1], acc[i][2], acc[i][3]);
            }
            *(float4*)&C[(size_t)gr * D + col0] = o;
        }
    }
}

// ---------------- CSR build ----------------
__global__ void zero_int_kernel(int* __restrict__ p, int n) {
    int i = blockIdx.x * blockDim.x + threadIdx.x;
    if (i < n) p[i] = 0;
}

__global__ void hist_kernel(const int* __restrict__ dst, int* __restrict__ deg, int nE) {
    int e = blockIdx.x * blockDim.x + threadIdx.x;
    if (e < nE) atomicAdd(&deg[dst[e]], 1);
}

// single-block exclusive scan over deg[0..n) -> rs, cur; rs[n] = total
__global__ __launch_bounds__(1024) void scan_kernel(const int* __restrict__ deg,
                                                    int* __restrict__ rs,
                                                    int* __restrict__ cur, int n) {
    __shared__ int wsum[16];
    __shared__ int woff[16];
    __shared__ int carry_s;
    int tid = threadIdx.x;
    int lane = tid & 63, wv = tid >> 6;
    if (tid == 0) carry_s = 0;
    __syncthreads();
    for (int base = 0; base < n; base += 1024) {
        int i = base + tid;
        int v = (i < n) ? deg[i] : 0;
        // wave inclusive scan
        int x = v;
#pragma unroll
        for (int off = 1; off < 64; off <<= 1) {
            int t = __shfl_up(x, off, 64);
            if (lane >= off) x += t;
        }
        if (lane == 63) wsum[wv] = x;
        __syncthreads();
        if (tid == 0) {
            int s = 0;
#pragma unroll
            for (int w = 0; w < 16; ++w) { woff[w] = s; s += wsum[w]; }
            wsum[15] = s;   // chunk total (stash)
        }
        __syncthreads();
        int excl = carry_s + woff[wv] + x - v;
        if (i < n) { rs[i] = excl; cur[i] = excl; }
        int chunk_total = wsum[15] + (wv == 15 ? 0 : 0); // read after barrier below
        __syncthreads();
        if (tid == 0) carry_s += chunk_total;
        __syncthreads();
    }
    if (tid == 0) rs[n] = carry_s;
}

__global__ void scatter_kernel(const int* __restrict__ src, const int* __restrict__ dst,
                               const float* __restrict__ val, int* __restrict__ cur,
                               int* __restrict__ csr_src, float* __restrict__ csr_val, int nE) {
    int e = blockIdx.x * blockDim.x + threadIdx.x;
    if (e < nE) {
        int p = atomicAdd(&cur[dst[e]], 1);
        csr_src[p] = src[e];
        csr_val[p] = val[e];
    }
}

// ---------------- pull aggregation + fused RReLU ----------------
// one wave per destination node; lane covers 4 consecutive features
__global__ __launch_bounds__(256) void agg_csr_kernel(const float* __restrict__ XW,
                                                      const int* __restrict__ csr_src,
                                                      const float* __restrict__ csr_val,
                                                      const int* __restrict__ rs,
                                                      float* __restrict__ out) {
    int d = blockIdx.x * 4 + (threadIdx.x >> 6);
    if (d >= NN) return;
    int lane = threadIdx.x & 63;
    int beg = rs[d], end = rs[d + 1];
    float ax = 0.f, ay = 0.f, az = 0.f, aw = 0.f;
    int i = beg;
    for (; i + 1 < end; i += 2) {
        int   s0 = csr_src[i],   s1 = csr_src[i + 1];
        float v0 = csr_val[i],   v1 = csr_val[i + 1];
        float4 x0 = *(const float4*)&XW[(size_t)s0 * D + lane * 4];
        float4 x1 = *(const float4*)&XW[(size_t)s1 * D + lane * 4];
        ax += v0 * x0.x + v1 * x1.x;
        ay += v0 * x0.y + v1 * x1.y;
        az += v0 * x0.z + v1 * x1.z;
        aw += v0 * x0.w + v1 * x1.w;
    }
    if (i < end) {
        int s0 = csr_src[i];
        float v0 = csr_val[i];
        float4 x0 = *(const float4*)&XW[(size_t)s0 * D + lane * 4];
        ax += v0 * x0.x; ay += v0 * x0.y; az += v0 * x0.z; aw += v0 * x0.w;
    }
    float4 o;
    o.x = (ax >= 0.f) ? ax : SLOPE_F * ax;
    o.y = (ay >= 0.f) ? ay : SLOPE_F * ay;
    o.z = (az >= 0.f) ? az : SLOPE_F * az;
    o.w = (aw >= 0.f) ? aw : SLOPE_F * aw;
    *(float4*)&out[(size_t)d * D + lane * 4] = o;
}

// ---------------- final: logits = hid@W2 + b2 ; log_softmax over 16 classes ----------------
__global__ void mlp2_kernel(const float* __restrict__ hid, const float* __restrict__ W2,
                            const float* __restrict__ b2, float* __restrict__ out, int M) {
    int tid = threadIdx.x;
    int n = blockIdx.x * 16 + (tid >> 4);
    int c = tid & 15;
    if (n >= M) return;
    float acc = b2[c];
    for (int k = 0; k < D; ++k)
        acc += hid[(size_t)n * D + k] * W2[k * 16 + c];
    float m = acc;
#pragma unroll
    for (int off = 1; off < 16; off <<= 1)
        m = fmaxf(m, __shfl_xor(m, off, 16));
    float ex = expf(acc - m);
    float s = ex;
#pragma unroll
    for (int off = 1; off < 16; off <<= 1)
        s += __shfl_xor(s, off, 16);
    out[(size_t)n * 16 + c] = acc - m - logf(s);
}

extern "C" void kernel_launch(void* const* d_in, const int* in_sizes, int n_in,
                              void* d_out, int out_size, void* d_ws, size_t ws_size,
                              hipStream_t stream) {
    const float* node_feats = (const float*)d_in[0];
    const float* edge_val   = (const float*)d_in[1];
    const float* l0_Wz = (const float*)d_in[2];
    const float* l0_Uz = (const float*)d_in[3];
    const float* l0_bz = (const float*)d_in[4];
    const float* l0_Wr = (const float*)d_in[5];
    const float* l0_Ur = (const float*)d_in[6];
    const float* l0_br = (const float*)d_in[7];
    const float* l0_Wh = (const float*)d_in[8];
    const float* l0_Uh = (const float*)d_in[9];
    const float* l0_bh = (const float*)d_in[10];
    const float* l0_Q0 = (const float*)d_in[11];
    const float* l1_Wz = (const float*)d_in[12];
    const float* l1_Uz = (const float*)d_in[13];
    const float* l1_bz = (const float*)d_in[14];
    const float* l1_Wr = (const float*)d_in[15];
    const float* l1_Ur = (const float*)d_in[16];
    const float* l1_br = (const float*)d_in[17];
    const float* l1_Wh = (const float*)d_in[18];
    const float* l1_Uh = (const float*)d_in[19];
    const float* l1_bh = (const float*)d_in[20];
    const float* l1_Q0 = (const float*)d_in[21];
    const float* W1 = (const float*)d_in[22];
    const float* b1 = (const float*)d_in[23];
    const float* W2 = (const float*)d_in[24];
    const float* b2 = (const float*)d_in[25];
    const int* e_src = (const int*)d_in[26];
    const int* e_dst = (const int*)d_in[27];
    float* out = (float*)d_out;

    // workspace layout
    const size_t BIG = (size_t)NN * D;   // 12.8M floats
    float* ws   = (float*)d_ws;
    float* X    = ws;                    // GEMM outputs
    float* Y    = ws + BIG;              // aggregation outputs
    float* sm   = ws + 2 * BIG;          // GRU scratch: 12 x 65536 floats
    float* Mz0  = sm + 0 * 65536;
    float* Mr0  = sm + 1 * 65536;
    float* q0   = sm + 2 * 65536;
    float* Mz1  = sm + 3 * 65536;
    float* Mr1  = sm + 4 * 65536;
    float* q1   = sm + 5 * 65536;
    float* zb   = sm + 6 * 65536;        // 2 layers
    float* RQ   = sm + 8 * 65536;        // 2 layers
    float* WhQ  = sm + 10 * 65536;       // 2 layers
    float* tail = sm + 12 * 65536;
    int*   csr_src = (int*)tail;                 // EE ints
    float* csr_val = (float*)(csr_src + EE);     // EE floats
    int*   deg  = (int*)(csr_val + EE);          // NN
    int*   rs   = deg + NN;                      // NN+1
    int*   cur  = rs + NN + 1;                   // NN

    // --- weight evolution (only final Q matters) ---
    prep_kernel<<<256, 256, 0, stream>>>(l0_Wz, l0_Uz, l0_Wr, l0_Ur, l0_Q0,
                                         l1_Wz, l1_Uz, l1_Wr, l1_Ur, l1_Q0,
                                         Mz0, Mr0, q0, Mz1, Mr1, q1);
    for (int t = 0; t < 6; ++t) {
        gruA_kernel<<<512, 256, 0, stream>>>(Mz0, Mr0, l0_Wh, l0_bz, l0_br, q0,
                                             Mz1, Mr1, l1_Wh, l1_bz, l1_br, q1,
                                             zb, RQ, WhQ);
        gruB_kernel<<<512, 256, 0, stream>>>(l0_Uh, l0_bh, q0, l1_Uh, l1_bh, q1,
                                             zb, RQ, WhQ);
    }

    // --- only timestep 5 contributes ---
    const float* feats5 = node_feats + (size_t)5 * BIG;
    const int*   src5   = e_src + (size_t)5 * EE;
    const int*   dst5   = e_dst + (size_t)5 * EE;
    const float* val5   = edge_val + (size_t)5 * EE;

    // --- CSR build (once; reused for both layers) ---
    zero_int_kernel<<<(NN + 255) / 256, 256, 0, stream>>>(deg, NN);
    hist_kernel<<<(EE + 255) / 256, 256, 0, stream>>>(dst5, deg, EE);
    scan_kernel<<<1, 1024, 0, stream>>>(deg, rs, cur, NN);
    scatter_kernel<<<(EE + 255) / 256, 256, 0, stream>>>(src5, dst5, val5, cur,
                                                         csr_src, csr_val, EE);

    dim3 gemm_grid((NN + 63) / 64, 4);
    const int ablocks = (NN + 3) / 4;    // 12500

    // layer 0 @ t=5
    gemm_k<0><<<gemm_grid, 256, 0, stream>>>(feats5, q0, nullptr, X, NN);
    agg_csr_kernel<<<ablocks, 256, 0, stream>>>(X, csr_src, csr_val, rs, Y);

    // layer 1 @ t=5
    gemm_k<0><<<gemm_grid, 256, 0, stream>>>(Y, q1, nullptr, X, NN);
    agg_csr_kernel<<<ablocks, 256, 0, stream>>>(X, csr_src, csr_val, rs, Y);

    // MLP head
    gemm_k<1><<<gemm_grid, 256, 0, stream>>>(Y, W1, b1, X, NN);
    mlp2_kernel<<<(NN + 15) / 16, 256, 0, stream>>>(X, W2, b2, out, NN);
}

// Round 3
// 1142.806 us; speedup vs baseline: 9.8441x; 1.0169x over previous
//
#include <hip/hip_runtime.h>
#include <cstddef>

#define SLOPE_F (11.0f / 48.0f)

static const int NN = 50000;     // nodes
static const int EE = 1600000;   // edges per timestep
static const int D  = 256;

typedef __attribute__((ext_vector_type(8))) short short8;
typedef __attribute__((ext_vector_type(4))) float f32x4;

__device__ __forceinline__ ushort f2bf(float f) {
    unsigned u = __float_as_uint(f);
    unsigned r = (u + 0x7fffu + ((u >> 16) & 1u)) >> 16;
    return (ushort)r;
}
__device__ __forceinline__ float bf2f(ushort u) {
    return __uint_as_float(((unsigned)u) << 16);
}

// ---------------- prep: merged GRU weights + Q init ----------------
__global__ void prep_kernel(const float* __restrict__ Wz0, const float* __restrict__ Uz0,
                            const float* __restrict__ Wr0, const float* __restrict__ Ur0,
                            const float* __restrict__ Q00,
                            const float* __restrict__ Wz1, const float* __restrict__ Uz1,
                            const float* __restrict__ Wr1, const float* __restrict__ Ur1,
                            const float* __restrict__ Q01,
                            float* __restrict__ Mz0, float* __restrict__ Mr0, float* __restrict__ q0,
                            float* __restrict__ Mz1, float* __restrict__ Mr1, float* __restrict__ q1) {
    int i = blockIdx.x * blockDim.x + threadIdx.x;   // 65536 total
    Mz0[i] = Wz0[i] + Uz0[i];
    Mr0[i] = Wr0[i] + Ur0[i];
    q0[i]  = Q00[i];
    Mz1[i] = Wz1[i] + Uz1[i];
    Mr1[i] = Wr1[i] + Ur1[i];
    q1[i]  = Q01[i];
}

// ---------------- GRU step part A (both layers) ----------------
__global__ void gruA_kernel(const float* __restrict__ Mz0, const float* __restrict__ Mr0,
                            const float* __restrict__ Wh0, const float* __restrict__ bz0,
                            const float* __restrict__ br0, const float* __restrict__ Q0,
                            const float* __restrict__ Mz1, const float* __restrict__ Mr1,
                            const float* __restrict__ Wh1, const float* __restrict__ bz1,
                            const float* __restrict__ br1, const float* __restrict__ Q1,
                            float* __restrict__ zb, float* __restrict__ RQ,
                            float* __restrict__ WhQ) {
    int layer = blockIdx.x >> 8;
    int i = blockIdx.x & 255;
    int j = threadIdx.x;
    const float* Mz = layer ? Mz1 : Mz0;
    const float* Mr = layer ? Mr1 : Mr0;
    const float* Wh = layer ? Wh1 : Wh0;
    const float* bz = layer ? bz1 : bz0;
    const float* br = layer ? br1 : br0;
    const float* Q  = layer ? Q1  : Q0;
    float az = 0.f, ar = 0.f, ah = 0.f;
    for (int k = 0; k < D; ++k) {
        float q  = Q[k * D + j];
        az += Mz[i * D + k] * q;
        ar += Mr[i * D + k] * q;
        ah += Wh[i * D + k] * q;
    }
    float zz = 1.f / (1.f + expf(-(az + bz[i * D + j])));
    float rr = 1.f / (1.f + expf(-(ar + br[i * D + j])));
    size_t o = (size_t)layer * 65536 + i * D + j;
    zb[o]  = zz;
    RQ[o]  = rr * Q[i * D + j];
    WhQ[o] = ah;
}

// ---------------- GRU step part B (both layers) ----------------
__global__ void gruB_kernel(const float* __restrict__ Uh0, const float* __restrict__ bh0,
                            float* __restrict__ Q0,
                            const float* __restrict__ Uh1, const float* __restrict__ bh1,
                            float* __restrict__ Q1,
                            const float* __restrict__ zb, const float* __restrict__ RQ,
                            const float* __restrict__ WhQ) {
    int layer = blockIdx.x >> 8;
    int i = blockIdx.x & 255;
    int j = threadIdx.x;
    const float* Uh = layer ? Uh1 : Uh0;
    const float* bh = layer ? bh1 : bh0;
    float* Q = layer ? Q1 : Q0;
    const float* RQl = RQ + (size_t)layer * 65536;
    float acc = 0.f;
    for (int k = 0; k < D; ++k)
        acc += Uh[i * D + k] * RQl[k * D + j];
    size_t o = (size_t)layer * 65536 + i * D + j;
    float h  = tanhf(WhQ[o] + acc + bh[i * D + j]);
    float zz = zb[o];
    float q  = Q[i * D + j];
    Q[i * D + j] = (1.f - zz) * q + zz * h;
}

// ---------------- convert A (fp32 -> bf16), 4 elts/thread ----------------
__global__ void convA_kernel(const float* __restrict__ in, ushort* __restrict__ out, int n4) {
    int i = blockIdx.x * blockDim.x + threadIdx.x;
    if (i < n4) {
        float4 v = ((const float4*)in)[i];
        ushort4 o;
        o.x = f2bf(v.x); o.y = f2bf(v.y); o.z = f2bf(v.z); o.w = f2bf(v.w);
        ((ushort4*)out)[i] = o;
    }
}

// ---------------- convert+transpose B: [k][n] fp32 -> Bt hi/lo [n][k] bf16 ----------------
// grid (256, 3): blockIdx.y selects matrix (q0, q1, W1); thread k, block n
__global__ void convB_kernel(const float* __restrict__ q0, const float* __restrict__ q1,
                             const float* __restrict__ W1, ushort* __restrict__ Bt) {
    int m = blockIdx.y;
    const float* src = (m == 0) ? q0 : ((m == 1) ? q1 : W1);
    int n = blockIdx.x;
    int k = threadIdx.x;
    float f = src[k * 256 + n];
    ushort hi = f2bf(f);
    ushort lo = f2bf(f - bf2f(hi));
    size_t base = (size_t)m * 131072;
    Bt[base + n * 256 + k]         = hi;
    Bt[base + 65536 + n * 256 + k] = lo;
}

// ---------------- MFMA GEMM: C[M,256] = A(bf16)[M,256] @ (Bhi+Blo)[256,256] ----------------
// Bt layout: [n][k] row-major (transposed), hi at +0, lo at +65536 elements.
// Block: 256 thr = 4 waves; BM=128 (wave = 32 rows x 256 cols).
template <int EPI>   // 0 = plain fp32 out, 1 = bias + relu
__global__ __launch_bounds__(256) void gemm_mfma(const ushort* __restrict__ A,
                                                 const ushort* __restrict__ Bt,
                                                 const float* __restrict__ bias,
                                                 float* __restrict__ C, int M) {
    int tid = threadIdx.x;
    int w = tid >> 6, l = tid & 63;
    int lr = l & 15;             // fragment row/col
    int lk = (l >> 4) << 3;      // k offset within 32-chunk
    int row0 = blockIdx.x * 128 + w * 32;

    f32x4 acc0[16] = {};
    f32x4 acc1[16] = {};

    int ra = row0 + lr;      if (ra > M - 1) ra = M - 1;
    int rb = row0 + 16 + lr; if (rb > M - 1) rb = M - 1;
    const ushort* Ap0 = A + (size_t)ra * 256 + lk;
    const ushort* Ap1 = A + (size_t)rb * 256 + lk;
    const ushort* Bp  = Bt + (size_t)lr * 256 + lk;

    for (int kc = 0; kc < 8; ++kc) {
        short8 a0 = *(const short8*)(Ap0 + kc * 32);
        short8 a1 = *(const short8*)(Ap1 + kc * 32);
#pragma unroll
        for (int n = 0; n < 16; ++n) {
            short8 bh = *(const short8*)(Bp + (size_t)n * 4096 + kc * 32);
            short8 bl = *(const short8*)(Bp + 65536 + (size_t)n * 4096 + kc * 32);
            acc0[n] = __builtin_amdgcn_mfma_f32_16x16x32_bf16(a0, bh, acc0[n], 0, 0, 0);
            acc0[n] = __builtin_amdgcn_mfma_f32_16x16x32_bf16(a0, bl, acc0[n], 0, 0, 0);
            acc1[n] = __builtin_amdgcn_mfma_f32_16x16x32_bf16(a1, bh, acc1[n], 0, 0, 0);
            acc1[n] = __builtin_amdgcn_mfma_f32_16x16x32_bf16(a1, bl, acc1[n], 0, 0, 0);
        }
    }

    int ro = (l >> 4) * 4;
#pragma unroll
    for (int n = 0; n < 16; ++n) {
        int gc = n * 16 + lr;
        float bb = (EPI == 1) ? bias[gc] : 0.f;
#pragma unroll
        for (int r = 0; r < 4; ++r) {
            int g0 = row0 + ro + r;
            if (g0 < M) {
                float v = acc0[n][r] + bb;
                if (EPI == 1) v = fmaxf(v, 0.f);
                C[(size_t)g0 * 256 + gc] = v;
            }
            int g1 = row0 + 16 + ro + r;
            if (g1 < M) {
                float v = acc1[n][r] + bb;
                if (EPI == 1) v = fmaxf(v, 0.f);
                C[(size_t)g1 * 256 + gc] = v;
            }
        }
    }
}

// ---------------- CSR build ----------------
__global__ void zero_int_kernel(int* __restrict__ p, int n) {
    int i = blockIdx.x * blockDim.x + threadIdx.x;
    if (i < n) p[i] = 0;
}

__global__ void hist_kernel(const int* __restrict__ dst, int* __restrict__ deg, int nE) {
    int e = blockIdx.x * blockDim.x + threadIdx.x;
    if (e < nE) atomicAdd(&deg[dst[e]], 1);
}

__global__ __launch_bounds__(1024) void scan_kernel(const int* __restrict__ deg,
                                                    int* __restrict__ rs,
                                                    int* __restrict__ cur, int n) {
    __shared__ int wsum[16];
    __shared__ int woff[16];
    __shared__ int carry_s;
    int tid = threadIdx.x;
    int lane = tid & 63, wv = tid >> 6;
    if (tid == 0) carry_s = 0;
    __syncthreads();
    for (int base = 0; base < n; base += 1024) {
        int i = base + tid;
        int v = (i < n) ? deg[i] : 0;
        int x = v;
#pragma unroll
        for (int off = 1; off < 64; off <<= 1) {
            int t = __shfl_up(x, off, 64);
            if (lane >= off) x += t;
        }
        if (lane == 63) wsum[wv] = x;
        __syncthreads();
        if (tid == 0) {
            int s = 0;
#pragma unroll
            for (int wq = 0; wq < 16; ++wq) { woff[wq] = s; s += wsum[wq]; }
            wsum[15] = s;
        }
        __syncthreads();
        int excl = carry_s + woff[wv] + x - v;
        if (i < n) { rs[i] = excl; cur[i] = excl; }
        int chunk_total = wsum[15];
        __syncthreads();
        if (tid == 0) carry_s += chunk_total;
        __syncthreads();
    }
    if (tid == 0) rs[n] = carry_s;
}

__global__ void scatter_kernel(const int* __restrict__ src, const int* __restrict__ dst,
                               const float* __restrict__ val, int* __restrict__ cur,
                               int* __restrict__ csr_src, float* __restrict__ csr_val, int nE) {
    int e = blockIdx.x * blockDim.x + threadIdx.x;
    if (e < nE) {
        int p = atomicAdd(&cur[dst[e]], 1);
        csr_src[p] = src[e];
        csr_val[p] = val[e];
    }
}

// ---------------- pull aggregation + fused RReLU -> bf16 out ----------------
__global__ __launch_bounds__(256) void agg_csr_kernel(const float* __restrict__ XW,
                                                      const int* __restrict__ csr_src,
                                                      const float* __restrict__ csr_val,
                                                      const int* __restrict__ rs,
                                                      ushort* __restrict__ out) {
    int d = blockIdx.x * 4 + (threadIdx.x >> 6);
    if (d >= NN) return;
    int lane = threadIdx.x & 63;
    int beg = rs[d], end = rs[d + 1];
    float ax = 0.f, ay = 0.f, az = 0.f, aw = 0.f;
    int i = beg;
    for (; i + 3 < end; i += 4) {
        int   s0 = csr_src[i],     s1 = csr_src[i + 1];
        int   s2 = csr_src[i + 2], s3 = csr_src[i + 3];
        float v0 = csr_val[i],     v1 = csr_val[i + 1];
        float v2 = csr_val[i + 2], v3 = csr_val[i + 3];
        float4 x0 = *(const float4*)&XW[(size_t)s0 * D + lane * 4];
        float4 x1 = *(const float4*)&XW[(size_t)s1 * D + lane * 4];
        float4 x2 = *(const float4*)&XW[(size_t)s2 * D + lane * 4];
        float4 x3 = *(const float4*)&XW[(size_t)s3 * D + lane * 4];
        ax += v0 * x0.x + v1 * x1.x + v2 * x2.x + v3 * x3.x;
        ay += v0 * x0.y + v1 * x1.y + v2 * x2.y + v3 * x3.y;
        az += v0 * x0.z + v1 * x1.z + v2 * x2.z + v3 * x3.z;
        aw += v0 * x0.w + v1 * x1.w + v2 * x2.w + v3 * x3.w;
    }
    for (; i < end; ++i) {
        int s0 = csr_src[i];
        float v0 = csr_val[i];
        float4 x0 = *(const float4*)&XW[(size_t)s0 * D + lane * 4];
        ax += v0 * x0.x; ay += v0 * x0.y; az += v0 * x0.z; aw += v0 * x0.w;
    }
    ax = (ax >= 0.f) ? ax : SLOPE_F * ax;
    ay = (ay >= 0.f) ? ay : SLOPE_F * ay;
    az = (az >= 0.f) ? az : SLOPE_F * az;
    aw = (aw >= 0.f) ? aw : SLOPE_F * aw;
    ushort4 o;
    o.x = f2bf(ax); o.y = f2bf(ay); o.z = f2bf(az); o.w = f2bf(aw);
    *(ushort4*)&out[(size_t)d * D + lane * 4] = o;
}

// ---------------- final: logits = hid@W2 + b2 ; log_softmax over 16 classes ----------------
__global__ void mlp2_kernel(const float* __restrict__ hid, const float* __restrict__ W2,
                            const float* __restrict__ b2, float* __restrict__ out, int M) {
    int tid = threadIdx.x;
    int n = blockIdx.x * 16 + (tid >> 4);
    int c = tid & 15;
    if (n >= M) return;
    float acc = b2[c];
    for (int k = 0; k < D; ++k)
        acc += hid[(size_t)n * D + k] * W2[k * 16 + c];
    float m = acc;
#pragma unroll
    for (int off = 1; off < 16; off <<= 1)
        m = fmaxf(m, __shfl_xor(m, off, 16));
    float ex = expf(acc - m);
    float s = ex;
#pragma unroll
    for (int off = 1; off < 16; off <<= 1)
        s += __shfl_xor(s, off, 16);
    out[(size_t)n * 16 + c] = acc - m - logf(s);
}

extern "C" void kernel_launch(void* const* d_in, const int* in_sizes, int n_in,
                              void* d_out, int out_size, void* d_ws, size_t ws_size,
                              hipStream_t stream) {
    const float* node_feats = (const float*)d_in[0];
    const float* edge_val   = (const float*)d_in[1];
    const float* l0_Wz = (const float*)d_in[2];
    const float* l0_Uz = (const float*)d_in[3];
    const float* l0_bz = (const float*)d_in[4];
    const float* l0_Wr = (const float*)d_in[5];
    const float* l0_Ur = (const float*)d_in[6];
    const float* l0_br = (const float*)d_in[7];
    const float* l0_Wh = (const float*)d_in[8];
    const float* l0_Uh = (const float*)d_in[9];
    const float* l0_bh = (const float*)d_in[10];
    const float* l0_Q0 = (const float*)d_in[11];
    const float* l1_Wz = (const float*)d_in[12];
    const float* l1_Uz = (const float*)d_in[13];
    const float* l1_bz = (const float*)d_in[14];
    const float* l1_Wr = (const float*)d_in[15];
    const float* l1_Ur = (const float*)d_in[16];
    const float* l1_br = (const float*)d_in[17];
    const float* l1_Wh = (const float*)d_in[18];
    const float* l1_Uh = (const float*)d_in[19];
    const float* l1_bh = (const float*)d_in[20];
    const float* l1_Q0 = (const float*)d_in[21];
    const float* W1 = (const float*)d_in[22];
    const float* b1 = (const float*)d_in[23];
    const float* W2 = (const float*)d_in[24];
    const float* b2 = (const float*)d_in[25];
    const int* e_src = (const int*)d_in[26];
    const int* e_dst = (const int*)d_in[27];
    float* out = (float*)d_out;

    // workspace layout
    const size_t BIG = (size_t)NN * D;   // 12.8M elements
    float* ws   = (float*)d_ws;
    float*  XW  = ws;                          // fp32 GEMM out / hid (12.8M floats)
    ushort* H   = (ushort*)(ws + BIG);         // bf16 activations (12.8M ushort = 6.4M floats)
    float*  sm  = ws + BIG + BIG / 2;          // GRU scratch: 12 x 65536 floats
    float* Mz0  = sm + 0 * 65536;
    float* Mr0  = sm + 1 * 65536;
    float* q0   = sm + 2 * 65536;
    float* Mz1  = sm + 3 * 65536;
    float* Mr1  = sm + 4 * 65536;
    float* q1   = sm + 5 * 65536;
    float* zb   = sm + 6 * 65536;
    float* RQ   = sm + 8 * 65536;
    float* WhQ  = sm + 10 * 65536;
    float* tail = sm + 12 * 65536;
    ushort* Bt  = (ushort*)tail;                    // 3 matrices x (hi+lo) x 65536
    int*   csr_src = (int*)(tail + 3 * 65536);      // EE ints
    float* csr_val = (float*)(csr_src + EE);        // EE floats
    int*   deg  = (int*)(csr_val + EE);             // NN
    int*   rs   = deg + NN;                         // NN+1
    int*   cur  = rs + NN + 1;                      // NN

    // --- weight evolution (only final Q matters) ---
    prep_kernel<<<256, 256, 0, stream>>>(l0_Wz, l0_Uz, l0_Wr, l0_Ur, l0_Q0,
                                         l1_Wz, l1_Uz, l1_Wr, l1_Ur, l1_Q0,
                                         Mz0, Mr0, q0, Mz1, Mr1, q1);
    for (int t = 0; t < 6; ++t) {
        gruA_kernel<<<512, 256, 0, stream>>>(Mz0, Mr0, l0_Wh, l0_bz, l0_br, q0,
                                             Mz1, Mr1, l1_Wh, l1_bz, l1_br, q1,
                                             zb, RQ, WhQ);
        gruB_kernel<<<512, 256, 0, stream>>>(l0_Uh, l0_bh, q0, l1_Uh, l1_bh, q1,
                                             zb, RQ, WhQ);
    }

    // --- only timestep 5 contributes ---
    const float* feats5 = node_feats + (size_t)5 * BIG;
    const int*   src5   = e_src + (size_t)5 * EE;
    const int*   dst5   = e_dst + (size_t)5 * EE;
    const float* val5   = edge_val + (size_t)5 * EE;

    // --- weight conversion (after GRU), activation conversion ---
    dim3 convb_grid(256, 3);
    convB_kernel<<<convb_grid, 256, 0, stream>>>(q0, q1, W1, Bt);
    convA_kernel<<<(int)(BIG / 4 + 255) / 256, 256, 0, stream>>>(feats5, H, (int)(BIG / 4));

    // --- CSR build (once; reused for both layers) ---
    zero_int_kernel<<<(NN + 255) / 256, 256, 0, stream>>>(deg, NN);
    hist_kernel<<<(EE + 255) / 256, 256, 0, stream>>>(dst5, deg, EE);
    scan_kernel<<<1, 1024, 0, stream>>>(deg, rs, cur, NN);
    scatter_kernel<<<(EE + 255) / 256, 256, 0, stream>>>(src5, dst5, val5, cur,
                                                         csr_src, csr_val, EE);

    const int gemm_blocks = (NN + 127) / 128;   // 391
    const int ablocks = (NN + 3) / 4;           // 12500

    // layer 0 @ t=5   (H holds bf16 feats; agg overwrites H with bf16 h1)
    gemm_mfma<0><<<gemm_blocks, 256, 0, stream>>>(H, Bt + 0 * 131072, nullptr, XW, NN);
    agg_csr_kernel<<<ablocks, 256, 0, stream>>>(XW, csr_src, csr_val, rs, H);

    // layer 1 @ t=5
    gemm_mfma<0><<<gemm_blocks, 256, 0, stream>>>(H, Bt + 1 * 131072, nullptr, XW, NN);
    agg_csr_kernel<<<ablocks, 256, 0, stream>>>(XW, csr_src, csr_val, rs, H);

    // MLP head (hid fp32 into XW buffer)
    gemm_mfma<1><<<gemm_blocks, 256, 0, stream>>>(H, Bt + 2 * 131072, b1, XW, NN);
    mlp2_kernel<<<(NN + 15) / 16, 256, 0, stream>>>(XW, W2, b2, out, NN);
}

// Round 4
// 930.613 us; speedup vs baseline: 12.0886x; 1.2280x over previous
//
#include <hip/hip_runtime.h>
#include <cstddef>

#define SLOPE_F (11.0f / 48.0f)

static const int NN = 50000;     // nodes
static const int EE = 1600000;   // edges per timestep
static const int D  = 256;

typedef __attribute__((ext_vector_type(8))) short short8;
typedef __attribute__((ext_vector_type(4))) float f32x4;

__device__ __forceinline__ ushort f2bf(float f) {
    unsigned u = __float_as_uint(f);
    unsigned r = (u + 0x7fffu + ((u >> 16) & 1u)) >> 16;
    return (ushort)r;
}
__device__ __forceinline__ float bf2f(ushort u) {
    return __uint_as_float(((unsigned)u) << 16);
}

// ---------------- prep: merged GRU weights + Q init ----------------
__global__ void prep_kernel(const float* __restrict__ Wz0, const float* __restrict__ Uz0,
                            const float* __restrict__ Wr0, const float* __restrict__ Ur0,
                            const float* __restrict__ Q00,
                            const float* __restrict__ Wz1, const float* __restrict__ Uz1,
                            const float* __restrict__ Wr1, const float* __restrict__ Ur1,
                            const float* __restrict__ Q01,
                            float* __restrict__ Mz0, float* __restrict__ Mr0, float* __restrict__ q0,
                            float* __restrict__ Mz1, float* __restrict__ Mr1, float* __restrict__ q1) {
    int i = blockIdx.x * blockDim.x + threadIdx.x;   // 65536 total
    Mz0[i] = Wz0[i] + Uz0[i];
    Mr0[i] = Wr0[i] + Ur0[i];
    q0[i]  = Q00[i];
    Mz1[i] = Wz1[i] + Uz1[i];
    Mr1[i] = Wr1[i] + Ur1[i];
    q1[i]  = Q01[i];
}

// ---------------- GRU step part A (both layers) ----------------
__global__ void gruA_kernel(const float* __restrict__ Mz0, const float* __restrict__ Mr0,
                            const float* __restrict__ Wh0, const float* __restrict__ bz0,
                            const float* __restrict__ br0, const float* __restrict__ Q0,
                            const float* __restrict__ Mz1, const float* __restrict__ Mr1,
                            const float* __restrict__ Wh1, const float* __restrict__ bz1,
                            const float* __restrict__ br1, const float* __restrict__ Q1,
                            float* __restrict__ zb, float* __restrict__ RQ,
                            float* __restrict__ WhQ) {
    int layer = blockIdx.x >> 8;
    int i = blockIdx.x & 255;
    int j = threadIdx.x;
    const float* Mz = layer ? Mz1 : Mz0;
    const float* Mr = layer ? Mr1 : Mr0;
    const float* Wh = layer ? Wh1 : Wh0;
    const float* bz = layer ? bz1 : bz0;
    const float* br = layer ? br1 : br0;
    const float* Q  = layer ? Q1  : Q0;
    float az = 0.f, ar = 0.f, ah = 0.f;
    for (int k = 0; k < D; ++k) {
        float q  = Q[k * D + j];
        az += Mz[i * D + k] * q;
        ar += Mr[i * D + k] * q;
        ah += Wh[i * D + k] * q;
    }
    float zz = 1.f / (1.f + expf(-(az + bz[i * D + j])));
    float rr = 1.f / (1.f + expf(-(ar + br[i * D + j])));
    size_t o = (size_t)layer * 65536 + i * D + j;
    zb[o]  = zz;
    RQ[o]  = rr * Q[i * D + j];
    WhQ[o] = ah;
}

// ---------------- GRU step part B (both layers) ----------------
__global__ void gruB_kernel(const float* __restrict__ Uh0, const float* __restrict__ bh0,
                            float* __restrict__ Q0,
                            const float* __restrict__ Uh1, const float* __restrict__ bh1,
                            float* __restrict__ Q1,
                            const float* __restrict__ zb, const float* __restrict__ RQ,
                            const float* __restrict__ WhQ) {
    int layer = blockIdx.x >> 8;
    int i = blockIdx.x & 255;
    int j = threadIdx.x;
    const float* Uh = layer ? Uh1 : Uh0;
    const float* bh = layer ? bh1 : bh0;
    float* Q = layer ? Q1 : Q0;
    const float* RQl = RQ + (size_t)layer * 65536;
    float acc = 0.f;
    for (int k = 0; k < D; ++k)
        acc += Uh[i * D + k] * RQl[k * D + j];
    size_t o = (size_t)layer * 65536 + i * D + j;
    float h  = tanhf(WhQ[o] + acc + bh[i * D + j]);
    float zz = zb[o];
    float q  = Q[i * D + j];
    Q[i * D + j] = (1.f - zz) * q + zz * h;
}

// ---------------- convert A (fp32 -> bf16), 4 elts/thread ----------------
__global__ void convA_kernel(const float* __restrict__ in, ushort* __restrict__ out, int n4) {
    int i = blockIdx.x * blockDim.x + threadIdx.x;
    if (i < n4) {
        float4 v = ((const float4*)in)[i];
        ushort4 o;
        o.x = f2bf(v.x); o.y = f2bf(v.y); o.z = f2bf(v.z); o.w = f2bf(v.w);
        ((ushort4*)out)[i] = o;
    }
}

// ---------------- convert+transpose B: [k][n] fp32 -> Bt [n][k] bf16 ----------------
// grid (256, 3): blockIdx.y selects matrix (q0, q1, W1); thread k, block n
__global__ void convB_kernel(const float* __restrict__ q0, const float* __restrict__ q1,
                             const float* __restrict__ W1, ushort* __restrict__ Bt) {
    int m = blockIdx.y;
    const float* src = (m == 0) ? q0 : ((m == 1) ? q1 : W1);
    int n = blockIdx.x;
    int k = threadIdx.x;
    Bt[(size_t)m * 65536 + n * 256 + k] = f2bf(src[k * 256 + n]);
}

// ---------------- MFMA GEMM: C(bf16)[M,256] = A(bf16)[M,256] @ B[256,256] ----------------
// Bt: [n][k] bf16 row-major. Whole B staged in 128 KB LDS with XOR swizzle.
// 512 threads = 8 waves; each wave computes 16 rows x 256 cols per 128-row tile.
// Grid-stride over tiles (B staged once per block).
template <int EPI>   // 0 = plain bf16 out, 1 = bias + relu bf16 out
__global__ __launch_bounds__(512) void gemm_mfma(const ushort* __restrict__ A,
                                                 const ushort* __restrict__ Bt,
                                                 const float* __restrict__ bias,
                                                 ushort* __restrict__ C, int M, int ntiles) {
    __shared__ ushort Bl[65536];   // 128 KB
    int tid = threadIdx.x;

    // stage whole B: 256 B/thread, swizzled rows
#pragma unroll
    for (int i = 0; i < 16; ++i) {
        int c  = tid + i * 512;      // 16B chunk id
        int L  = c << 4;             // linear byte offset in Bt
        int n  = L >> 9;             // row (512 B rows)
        int kb = L & 511;
        short8 v = *(const short8*)((const char*)Bt + L);
        *(short8*)((char*)Bl + n * 512 + (kb ^ ((n & 7) << 4))) = v;
    }
    __syncthreads();

    int w = tid >> 6, l = tid & 63;
    int lr = l & 15;          // fragment row/col within 16
    int lk = l >> 4;          // 0..3 (k sub-chunk)

    for (int t = blockIdx.x; t < ntiles; t += gridDim.x) {
        int row0 = t * 128 + w * 16;
        int ra = row0 + lr; if (ra > M - 1) ra = M - 1;
        const ushort* Ap = A + (size_t)ra * 256 + lk * 8;

        f32x4 acc[16] = {};
        short8 a = *(const short8*)Ap;   // prefetch kc=0
#pragma unroll
        for (int kc = 0; kc < 8; ++kc) {
            short8 ac = a;
            if (kc < 7) a = *(const short8*)(Ap + (kc + 1) * 32);
            int kb = kc * 64 + lk * 16;
#pragma unroll
            for (int nb = 0; nb < 16; ++nb) {
                int n = nb * 16 + lr;
                short8 bf = *(const short8*)((const char*)Bl + n * 512 + (kb ^ ((lr & 7) << 4)));
                acc[nb] = __builtin_amdgcn_mfma_f32_16x16x32_bf16(ac, bf, acc[nb], 0, 0, 0);
            }
        }

        int ro = lk * 4;
#pragma unroll
        for (int nb = 0; nb < 16; ++nb) {
            int gc = nb * 16 + lr;
            float bb = (EPI == 1) ? bias[gc] : 0.f;
#pragma unroll
            for (int q = 0; q < 4; ++q) {
                int g = row0 + ro + q;
                if (g < M) {
                    float v = acc[nb][q];
                    if (EPI == 1) v = fmaxf(v + bb, 0.f);
                    C[(size_t)g * 256 + gc] = f2bf(v);
                }
            }
        }
    }
}

// ---------------- CSR build ----------------
__global__ void zero_int_kernel(int* __restrict__ p, int n) {
    int i = blockIdx.x * blockDim.x + threadIdx.x;
    if (i < n) p[i] = 0;
}

__global__ void hist_kernel(const int* __restrict__ dst, int* __restrict__ deg, int nE) {
    int e = blockIdx.x * blockDim.x + threadIdx.x;
    if (e < nE) atomicAdd(&deg[dst[e]], 1);
}

__global__ __launch_bounds__(1024) void scan_kernel(const int* __restrict__ deg,
                                                    int* __restrict__ rs,
                                                    int* __restrict__ cur, int n) {
    __shared__ int wsum[16];
    __shared__ int woff[16];
    __shared__ int carry_s;
    int tid = threadIdx.x;
    int lane = tid & 63, wv = tid >> 6;
    if (tid == 0) carry_s = 0;
    __syncthreads();
    for (int base = 0; base < n; base += 1024) {
        int i = base + tid;
        int v = (i < n) ? deg[i] : 0;
        int x = v;
#pragma unroll
        for (int off = 1; off < 64; off <<= 1) {
            int t = __shfl_up(x, off, 64);
            if (lane >= off) x += t;
        }
        if (lane == 63) wsum[wv] = x;
        __syncthreads();
        if (tid == 0) {
            int s = 0;
#pragma unroll
            for (int wq = 0; wq < 16; ++wq) { woff[wq] = s; s += wsum[wq]; }
            wsum[15] = s;
        }
        __syncthreads();
        int excl = carry_s + woff[wv] + x - v;
        if (i < n) { rs[i] = excl; cur[i] = excl; }
        int chunk_total = wsum[15];
        __syncthreads();
        if (tid == 0) carry_s += chunk_total;
        __syncthreads();
    }
    if (tid == 0) rs[n] = carry_s;
}

__global__ void scatter_kernel(const int* __restrict__ src, const int* __restrict__ dst,
                               const float* __restrict__ val, int* __restrict__ cur,
                               int* __restrict__ csr_src, float* __restrict__ csr_val, int nE) {
    int e = blockIdx.x * blockDim.x + threadIdx.x;
    if (e < nE) {
        int p = atomicAdd(&cur[dst[e]], 1);
        csr_src[p] = src[e];
        csr_val[p] = val[e];
    }
}

// ---------------- pull aggregation (bf16 gather) + fused RReLU -> bf16 out ----------------
__global__ __launch_bounds__(256) void agg_csr_kernel(const ushort* __restrict__ XW,
                                                      const int* __restrict__ csr_src,
                                                      const float* __restrict__ csr_val,
                                                      const int* __restrict__ rs,
                                                      ushort* __restrict__ out) {
    int d = blockIdx.x * 4 + (threadIdx.x >> 6);
    if (d >= NN) return;
    int lane = threadIdx.x & 63;
    int beg = rs[d], end = rs[d + 1];
    float ax = 0.f, ay = 0.f, az = 0.f, aw = 0.f;
    int i = beg;
    for (; i + 7 < end; i += 8) {
        int s[8]; float v[8];
#pragma unroll
        for (int u = 0; u < 8; ++u) { s[u] = csr_src[i + u]; v[u] = csr_val[i + u]; }
#pragma unroll
        for (int u = 0; u < 8; ++u) {
            ushort4 x = *(const ushort4*)&XW[(size_t)s[u] * D + lane * 4];
            ax += v[u] * bf2f(x.x);
            ay += v[u] * bf2f(x.y);
            az += v[u] * bf2f(x.z);
            aw += v[u] * bf2f(x.w);
        }
    }
    for (; i < end; ++i) {
        int s0 = csr_src[i];
        float v0 = csr_val[i];
        ushort4 x = *(const ushort4*)&XW[(size_t)s0 * D + lane * 4];
        ax += v0 * bf2f(x.x); ay += v0 * bf2f(x.y);
        az += v0 * bf2f(x.z); aw += v0 * bf2f(x.w);
    }
    ax = (ax >= 0.f) ? ax : SLOPE_F * ax;
    ay = (ay >= 0.f) ? ay : SLOPE_F * ay;
    az = (az >= 0.f) ? az : SLOPE_F * az;
    aw = (aw >= 0.f) ? aw : SLOPE_F * aw;
    ushort4 o;
    o.x = f2bf(ax); o.y = f2bf(ay); o.z = f2bf(az); o.w = f2bf(aw);
    *(ushort4*)&out[(size_t)d * D + lane * 4] = o;
}

// ---------------- final: logits = hid@W2 + b2 ; log_softmax over 16 classes ----------------
__global__ void mlp2_kernel(const ushort* __restrict__ hid, const float* __restrict__ W2,
                            const float* __restrict__ b2, float* __restrict__ out, int M) {
    int tid = threadIdx.x;
    int n = blockIdx.x * 16 + (tid >> 4);
    int c = tid & 15;
    if (n >= M) return;
    float acc = b2[c];
    const ushort* hp = hid + (size_t)n * D;
    for (int k = 0; k < D; k += 4) {
        ushort4 h4 = *(const ushort4*)(hp + k);
        acc += bf2f(h4.x) * W2[(k + 0) * 16 + c] + bf2f(h4.y) * W2[(k + 1) * 16 + c]
             + bf2f(h4.z) * W2[(k + 2) * 16 + c] + bf2f(h4.w) * W2[(k + 3) * 16 + c];
    }
    float m = acc;
#pragma unroll
    for (int off = 1; off < 16; off <<= 1)
        m = fmaxf(m, __shfl_xor(m, off, 16));
    float ex = expf(acc - m);
    float s = ex;
#pragma unroll
    for (int off = 1; off < 16; off <<= 1)
        s += __shfl_xor(s, off, 16);
    out[(size_t)n * 16 + c] = acc - m - logf(s);
}

extern "C" void kernel_launch(void* const* d_in, const int* in_sizes, int n_in,
                              void* d_out, int out_size, void* d_ws, size_t ws_size,
                              hipStream_t stream) {
    const float* node_feats = (const float*)d_in[0];
    const float* edge_val   = (const float*)d_in[1];
    const float* l0_Wz = (const float*)d_in[2];
    const float* l0_Uz = (const float*)d_in[3];
    const float* l0_bz = (const float*)d_in[4];
    const float* l0_Wr = (const float*)d_in[5];
    const float* l0_Ur = (const float*)d_in[6];
    const float* l0_br = (const float*)d_in[7];
    const float* l0_Wh = (const float*)d_in[8];
    const float* l0_Uh = (const float*)d_in[9];
    const float* l0_bh = (const float*)d_in[10];
    const float* l0_Q0 = (const float*)d_in[11];
    const float* l1_Wz = (const float*)d_in[12];
    const float* l1_Uz = (const float*)d_in[13];
    const float* l1_bz = (const float*)d_in[14];
    const float* l1_Wr = (const float*)d_in[15];
    const float* l1_Ur = (const float*)d_in[16];
    const float* l1_br = (const float*)d_in[17];
    const float* l1_Wh = (const float*)d_in[18];
    const float* l1_Uh = (const float*)d_in[19];
    const float* l1_bh = (const float*)d_in[20];
    const float* l1_Q0 = (const float*)d_in[21];
    const float* W1 = (const float*)d_in[22];
    const float* b1 = (const float*)d_in[23];
    const float* W2 = (const float*)d_in[24];
    const float* b2 = (const float*)d_in[25];
    const int* e_src = (const int*)d_in[26];
    const int* e_dst = (const int*)d_in[27];
    float* out = (float*)d_out;

    // workspace layout
    const size_t BIG = (size_t)NN * D;   // 12.8M elements
    ushort* XWb = (ushort*)d_ws;                    // bf16 GEMM out (12.8M ushort)
    ushort* H   = XWb + BIG;                        // bf16 activations
    float*  sm  = (float*)(H + BIG);                // GRU scratch: 12 x 65536 floats
    float* Mz0  = sm + 0 * 65536;
    float* Mr0  = sm + 1 * 65536;
    float* q0   = sm + 2 * 65536;
    float* Mz1  = sm + 3 * 65536;
    float* Mr1  = sm + 4 * 65536;
    float* q1   = sm + 5 * 65536;
    float* zb   = sm + 6 * 65536;
    float* RQ   = sm + 8 * 65536;
    float* WhQ  = sm + 10 * 65536;
    float* tail = sm + 12 * 65536;
    ushort* Bt  = (ushort*)tail;                    // 3 x 65536 bf16
    int*   csr_src = (int*)(Bt + 3 * 65536);        // EE ints
    float* csr_val = (float*)(csr_src + EE);        // EE floats
    int*   deg  = (int*)(csr_val + EE);             // NN
    int*   rs   = deg + NN;                         // NN+1
    int*   cur  = rs + NN + 1;                      // NN

    // --- weight evolution (only final Q matters) ---
    prep_kernel<<<256, 256, 0, stream>>>(l0_Wz, l0_Uz, l0_Wr, l0_Ur, l0_Q0,
                                         l1_Wz, l1_Uz, l1_Wr, l1_Ur, l1_Q0,
                                         Mz0, Mr0, q0, Mz1, Mr1, q1);
    for (int t = 0; t < 6; ++t) {
        gruA_kernel<<<512, 256, 0, stream>>>(Mz0, Mr0, l0_Wh, l0_bz, l0_br, q0,
                                             Mz1, Mr1, l1_Wh, l1_bz, l1_br, q1,
                                             zb, RQ, WhQ);
        gruB_kernel<<<512, 256, 0, stream>>>(l0_Uh, l0_bh, q0, l1_Uh, l1_bh, q1,
                                             zb, RQ, WhQ);
    }

    // --- only timestep 5 contributes ---
    const float* feats5 = node_feats + (size_t)5 * BIG;
    const int*   src5   = e_src + (size_t)5 * EE;
    const int*   dst5   = e_dst + (size_t)5 * EE;
    const float* val5   = edge_val + (size_t)5 * EE;

    // --- weight + activation conversion ---
    dim3 convb_grid(256, 3);
    convB_kernel<<<convb_grid, 256, 0, stream>>>(q0, q1, W1, Bt);
    convA_kernel<<<(int)(BIG / 4 + 255) / 256, 256, 0, stream>>>(feats5, H, (int)(BIG / 4));

    // --- CSR build (once; reused for both layers) ---
    zero_int_kernel<<<(NN + 255) / 256, 256, 0, stream>>>(deg, NN);
    hist_kernel<<<(EE + 255) / 256, 256, 0, stream>>>(dst5, deg, EE);
    scan_kernel<<<1, 1024, 0, stream>>>(deg, rs, cur, NN);
    scatter_kernel<<<(EE + 255) / 256, 256, 0, stream>>>(src5, dst5, val5, cur,
                                                         csr_src, csr_val, EE);

    const int ntiles = (NN + 127) / 128;        // 391
    const int gemm_blocks = (ntiles + 1) / 2;   // 196 (grid-stride, B staged once)
    const int ablocks = (NN + 3) / 4;           // 12500

    // layer 0 @ t=5
    gemm_mfma<0><<<gemm_blocks, 512, 0, stream>>>(H, Bt + 0 * 65536, nullptr, XWb, NN, ntiles);
    agg_csr_kernel<<<ablocks, 256, 0, stream>>>(XWb, csr_src, csr_val, rs, H);

    // layer 1 @ t=5
    gemm_mfma<0><<<gemm_blocks, 512, 0, stream>>>(H, Bt + 1 * 65536, nullptr, XWb, NN, ntiles);
    agg_csr_kernel<<<ablocks, 256, 0, stream>>>(XWb, csr_src, csr_val, rs, H);

    // MLP head (bf16 hid into XWb)
    gemm_mfma<1><<<gemm_blocks, 512, 0, stream>>>(H, Bt + 2 * 65536, b1, XWb, NN, ntiles);
    mlp2_kernel<<<(NN + 15) / 16, 256, 0, stream>>>(XWb, W2, b2, out, NN);
}